// Round 11
// baseline (3137.462 us; speedup 1.0000x reference)
//
#include <hip/hip_runtime.h>
#include <math.h>

typedef __attribute__((ext_vector_type(4)))  int   i32x4;
typedef __attribute__((ext_vector_type(16))) int   i32x16;
typedef __attribute__((ext_vector_type(4)))  float f32x4;

namespace {
constexpr int IN_F   = 4096;
constexpr int OUT_F  = 4096;
constexpr int TOKENS = 8192;
constexpr int PACKED = IN_F / 16;      // 256 words per weight row

// fast-path gemm: 256x256 block, 8 waves (2M x 4N), wave tile 128x64,
// BK=128, A LDS double-buffer (64 KB, coalesced+swizzled staging),
// B packed 2-bit in registers (unpack16 per phase), 2 blocks/CU.
constexpr int BM   = 256;
constexpr int BN   = 256;
constexpr int BK   = 128;              // 8 chunks of 16 k
constexpr int NTHR = 512;
constexpr int NT   = IN_F / BK;        // 32 K-tiles

constexpr size_t XQ_BYTES  = (size_t)TOKENS * IN_F;        // 33.55 MB
constexpr size_t XS_BYTES  = (size_t)TOKENS * 4;           // 32 KB
constexpr size_t PWT_OFF   = XQ_BYTES + XS_BYTES;
constexpr size_t PWT_BYTES = (size_t)PACKED * OUT_F * 4;   // 4 MB ([c][n] u32)
constexpr size_t WS_NEED   = PWT_OFF + PWT_BYTES;          // ~37.6 MB
}

// 16x 2-bit {0,1,2}  ->  16x i8 {-1,0,1}  (4 dwords)
__device__ __forceinline__ i32x4 unpack16(unsigned w) {
  i32x4 r;
#pragma unroll
  for (int g = 0; g < 4; ++g) {
    unsigned t = (w >> (8 * g)) & 0xFFu;
    unsigned s = (t | (t << 6) | (t << 12) | (t << 18)) & 0x03030303u;
    r[g] = (int)((((s | 0x80808080u) - 0x01010101u) ^ 0x80808080u));
  }
  return r;
}

// -- pass 1 (fused): rowquant (blocks 0..2047) + PW transpose (256 blocks) --
// PWT layout: [c (k/16)][n] u32  -> gemm B loads are coalesced per half-wave.
__global__ __launch_bounds__(256)
void prep(const float* __restrict__ X, signed char* __restrict__ XQ,
          float* __restrict__ XS, const unsigned* __restrict__ PW,
          unsigned* __restrict__ PWT) {
  if (blockIdx.x < TOKENS / 4) {
    const int row  = blockIdx.x * 4 + (threadIdx.x >> 6);
    const int lane = threadIdx.x & 63;
    const float* xr = X + (size_t)row * IN_F;

    f32x4 v[16];
    float m = 0.f;
#pragma unroll
    for (int c = 0; c < 16; ++c) {
      v[c] = *(const f32x4*)(xr + c * 256 + lane * 4);
      m = fmaxf(m, fmaxf(fmaxf(fabsf(v[c].x), fabsf(v[c].y)),
                         fmaxf(fabsf(v[c].z), fabsf(v[c].w))));
    }
#pragma unroll
    for (int off = 32; off; off >>= 1) m = fmaxf(m, __shfl_xor(m, off, 64));
    m = fmaxf(m, 1e-5f);
    const float r = 127.f / m;

#pragma unroll
    for (int c = 0; c < 16; ++c) {
      int q0 = (int)rintf(v[c].x * r);
      int q1 = (int)rintf(v[c].y * r);
      int q2 = (int)rintf(v[c].z * r);
      int q3 = (int)rintf(v[c].w * r);
      unsigned d = (q0 & 255) | ((q1 & 255) << 8) | ((q2 & 255) << 16) | ((q3 & 255) << 24);
      *(unsigned*)(XQ + (size_t)row * IN_F + c * 256 + lane * 4) = d;
    }
    if (lane == 0) XS[row] = m;
  } else {
    // 64x64-tiled transpose PW [n][c] -> PWT [c][n], coalesced both sides
    __shared__ unsigned sm[64][65];
    const int b  = blockIdx.x - TOKENS / 4;    // 0..255
    const int bn = (b & 63) * 64;              // n-tile base (4096/64)
    const int bc = (b >> 6) * 64;              // c-tile base (256/64)
    const int tx = threadIdx.x & 63;
    const int ty = threadIdx.x >> 6;           // 0..3
#pragma unroll
    for (int j = 0; j < 16; ++j)
      sm[ty * 16 + j][tx] = PW[(size_t)(bn + ty * 16 + j) * PACKED + bc + tx];
    __syncthreads();
#pragma unroll
    for (int j = 0; j < 16; ++j)
      PWT[(size_t)(bc + ty * 16 + j) * OUT_F + bn + tx] = sm[tx][ty * 16 + j];
  }
}

// ---------------- pass 2 (fast): 4-phase i8 GEMM -----------------------
// A staging: COALESCED (8 threads/row cover 128 contiguous B) with XOR
// pre-swizzle on the GLOBAL source (LDS dest stays linear per gload_lds
// rule); ds_read applies the same XOR -> conflict-free both sides.
// LDS[row][c] = XQ[row][c ^ (row&7)]; read (row,c) at [row][c ^ (row&7)].
// B: 8 packed u32/lane/tile from PWT (coalesced), unpacked per phase.

#define FENCE asm volatile("" ::: "memory")

#define STAGE_A(BUFO_, KT_)                                                     \
  {                                                                             \
    _Pragma("unroll")                                                           \
    for (int j = 0; j < 4; ++j) {                                               \
      const int idx  = tid + j * 512;   /* row = idx>>3, c = idx&7 */           \
      const int row_ = idx >> 3;                                                \
      const int c_   = (idx & 7) ^ (row_ & 7);                                  \
      const signed char* src =                                                  \
          XQ + (size_t)(m0 + row_) * IN_F + (KT_) * BK + c_ * 16;               \
      signed char* dst = lA + (BUFO_) + (w * 64 + j * 512) * 16;                \
      __builtin_amdgcn_global_load_lds(                                         \
          (const __attribute__((address_space(1))) void*)src,                   \
          (__attribute__((address_space(3))) void*)dst, 16, 0, 0);              \
    }                                                                           \
  }

#define LOAD_B(B_, KT_)                                                         \
  {                                                                             \
    _Pragma("unroll")                                                           \
    for (int nf = 0; nf < 2; ++nf) {                                            \
      _Pragma("unroll")                                                         \
      for (int ks = 0; ks < 4; ++ks)                                            \
        B_[nf][ks] = PWT[(size_t)((KT_) * 8 + ks * 2 + h) * OUT_F +             \
                         n0 + wn * 64 + nf * 32 + l31];                         \
    }                                                                           \
  }

#define PHASE(KS_, BUFO_, B_)                                                   \
  {                                                                             \
    i32x4 afr[4], bfr[2];                                                       \
    _Pragma("unroll")                                                           \
    for (int mf = 0; mf < 4; ++mf) {                                            \
      const int row_ = wm * 128 + mf * 32 + l31;                                \
      afr[mf] = *(const i32x4*)(lA + (BUFO_) +                                  \
          (row_ * 8 + (((KS_) * 2 + h) ^ (row_ & 7))) * 16);                    \
    }                                                                           \
    bfr[0] = unpack16(B_[0][KS_]);                                              \
    bfr[1] = unpack16(B_[1][KS_]);                                              \
    __builtin_amdgcn_s_setprio(1);                                              \
    _Pragma("unroll")                                                           \
    for (int mf = 0; mf < 4; ++mf) {                                            \
      acc[mf][0] = __builtin_amdgcn_mfma_i32_32x32x32_i8(afr[mf], bfr[0],       \
                                                         acc[mf][0], 0, 0, 0);  \
      acc[mf][1] = __builtin_amdgcn_mfma_i32_32x32x32_i8(afr[mf], bfr[1],       \
                                                         acc[mf][1], 0, 0, 0);  \
    }                                                                           \
    __builtin_amdgcn_s_setprio(0);                                              \
  }

__global__ __launch_bounds__(NTHR, 4)
void gemm_i8(const signed char* __restrict__ XQ, const unsigned* __restrict__ PWT,
             const float* __restrict__ XS, const float* __restrict__ SC,
             float* __restrict__ OUT) {
  __shared__ signed char lA[2 * 32768];   // A: [buf][row 256][c 8][16], swizzled

  const int tid  = threadIdx.x;
  const int lane = tid & 63;
  const int w    = tid >> 6;     // 0..7
  const int wm   = w >> 2;       // 0..1 (M half)
  const int wn   = w & 3;        // 0..3 (N quarter)
  const int l31  = lane & 31;
  const int h    = lane >> 5;    // half-wave -> k-chunk parity

  // bijective XCD swizzle: 512 blocks = 8 XCD x 64; each XCD owns 2 n-tiles
  // (packed-B stripe 512 cols x 1 KB = 512 KB, L2-resident)
  const int orig = blockIdx.y * gridDim.x + blockIdx.x;
  const int xcd  = orig & 7;
  const int idx  = orig >> 3;                  // 0..63
  const int m0   = (idx >> 1) * BM;            // 32 m-tiles
  const int n0   = (xcd * 2 + (idx & 1)) * BN; // 16 n-tiles

  i32x16 acc[4][2];
#pragma unroll
  for (int mf = 0; mf < 4; ++mf)
#pragma unroll
    for (int nf = 0; nf < 2; ++nf)
      acc[mf][nf] = (i32x16)(0);

  unsigned Ba[2][4], Bb[2][4];

  // prologue: tile 0 (A -> buf0, B -> Ba); drain A(0) only (vmcnt 8 = B(0))
  STAGE_A(0, 0);
  FENCE;
  LOAD_B(Ba, 0);
  asm volatile("s_waitcnt vmcnt(8)" ::: "memory");
  __builtin_amdgcn_s_barrier();

  for (int kt = 0; kt < NT; kt += 2) {
    // tile kt (even): compute buf0/Ba; prefetch kt+1 -> buf1/Bb
    STAGE_A(32768, kt + 1);
    FENCE;
    LOAD_B(Bb, kt + 1);
    FENCE;
    PHASE(0, 0, Ba)
    PHASE(1, 0, Ba)
    PHASE(2, 0, Ba)
    PHASE(3, 0, Ba)
    asm volatile("s_waitcnt vmcnt(8)" ::: "memory");  // A(kt+1) resident
    __builtin_amdgcn_s_barrier();

    // tile kt+1 (odd): compute buf1/Bb; prefetch kt+2 -> buf0/Ba
    if (kt + 2 < NT) {
      STAGE_A(0, kt + 2);
      FENCE;
      LOAD_B(Ba, kt + 2);
      FENCE;
    }
    PHASE(0, 32768, Bb)
    PHASE(1, 32768, Bb)
    PHASE(2, 32768, Bb)
    PHASE(3, 32768, Bb)
    asm volatile("s_waitcnt vmcnt(8)" ::: "memory");
    __builtin_amdgcn_s_barrier();
  }

  // ---- epilogue: C/D (32x32): col=lane&31, row=(reg&3)+8*(reg>>2)+4*h ----
  const float sc = SC[0] / 127.f;
#pragma unroll
  for (int mf = 0; mf < 4; ++mf) {
    float fs[16];
#pragma unroll
    for (int r = 0; r < 16; ++r) {
      const int mm = m0 + wm * 128 + mf * 32 + 4 * h + (r & 3) + 8 * (r >> 2);
      fs[r] = sc * XS[mm];
    }
#pragma unroll
    for (int nf = 0; nf < 2; ++nf) {
      const int ncol = n0 + wn * 64 + nf * 32 + l31;
#pragma unroll
      for (int r = 0; r < 16; ++r) {
        const int mm = m0 + wm * 128 + mf * 32 + 4 * h + (r & 3) + 8 * (r >> 2);
        OUT[(size_t)mm * OUT_F + ncol] = (float)acc[mf][nf][r] * fs[r];
      }
    }
  }
}

// ------- pass 2 (fallback, ws-small): verified baseline gemm, inline B -------
__global__ __launch_bounds__(256, 2)
void gemm_i8_pw(const signed char* __restrict__ XQ, const unsigned* __restrict__ PW,
                const float* __restrict__ XS, const float* __restrict__ SC,
                float* __restrict__ OUT) {
  __shared__ signed char lA[256 * 128];

  const int tid  = threadIdx.x;
  const int lane = tid & 63;
  const int w    = tid >> 6;
  const int wm   = w >> 1;
  const int wn   = w & 1;
  const int l31  = lane & 31;
  const int h    = lane >> 5;

  const int m0 = blockIdx.y * 256;
  const int n0 = blockIdx.x * 128;

  i32x16 acc[4][2];
#pragma unroll
  for (int mf = 0; mf < 4; ++mf)
#pragma unroll
    for (int nf = 0; nf < 2; ++nf)
      acc[mf][nf] = (i32x16)(0);

  const unsigned* pb0 = PW + (size_t)(n0 + wn * 64 + 0 * 32 + l31) * PACKED;
  const unsigned* pb1 = PW + (size_t)(n0 + wn * 64 + 1 * 32 + l31) * PACKED;

  for (int kt = 0; kt < IN_F / 128; ++kt) {
#pragma unroll
    for (int cc = 0; cc < 2; ++cc) {
      const int c = w * 2 + cc;
#pragma unroll
      for (int rb = 0; rb < 4; ++rb) {
        const signed char* src =
            XQ + (size_t)(m0 + rb * 64 + lane) * IN_F + kt * 128 + c * 16;
        signed char* dst = lA + c * 4096 + rb * 1024;
        __builtin_amdgcn_global_load_lds(
            (const __attribute__((address_space(1))) void*)src,
            (__attribute__((address_space(3))) void*)dst, 16, 0, 0);
      }
    }

    unsigned bw0[4], bw1[4];
#pragma unroll
    for (int ks = 0; ks < 4; ++ks) {
      bw0[ks] = pb0[kt * 8 + ks * 2 + h];
      bw1[ks] = pb1[kt * 8 + ks * 2 + h];
    }

    __syncthreads();

#pragma unroll
    for (int ks = 0; ks < 4; ++ks) {
      i32x4 bfr0 = unpack16(bw0[ks]);
      i32x4 bfr1 = unpack16(bw1[ks]);
      i32x4 afr[4];
#pragma unroll
      for (int mf = 0; mf < 4; ++mf)
        afr[mf] = *(const i32x4*)(lA + (ks * 2 + h) * 4096 +
                                  (wm * 128 + mf * 32 + l31) * 16);
#pragma unroll
      for (int mf = 0; mf < 4; ++mf) {
        acc[mf][0] = __builtin_amdgcn_mfma_i32_32x32x32_i8(afr[mf], bfr0, acc[mf][0], 0, 0, 0);
        acc[mf][1] = __builtin_amdgcn_mfma_i32_32x32x32_i8(afr[mf], bfr1, acc[mf][1], 0, 0, 0);
      }
    }
    __syncthreads();
  }

  const float sc = SC[0] / 127.f;
#pragma unroll
  for (int mf = 0; mf < 4; ++mf) {
    float fs[16];
#pragma unroll
    for (int r = 0; r < 16; ++r) {
      const int mm = m0 + wm * 128 + mf * 32 + 4 * h + (r & 3) + 8 * (r >> 2);
      fs[r] = sc * XS[mm];
    }
#pragma unroll
    for (int nf = 0; nf < 2; ++nf) {
      const int ncol = n0 + wn * 64 + nf * 32 + l31;
#pragma unroll
      for (int r = 0; r < 16; ++r) {
        const int mm = m0 + wm * 128 + mf * 32 + 4 * h + (r & 3) + 8 * (r >> 2);
        OUT[(size_t)mm * OUT_F + ncol] = (float)acc[mf][nf][r] * fs[r];
      }
    }
  }
}

extern "C" void kernel_launch(void* const* d_in, const int* in_sizes, int n_in,
                              void* d_out, int out_size, void* d_ws, size_t ws_size,
                              hipStream_t stream) {
  const float*    x  = (const float*)d_in[0];
  const unsigned* pw = (const unsigned*)d_in[1];
  const float*    sc = (const float*)d_in[2];
  float*          out = (float*)d_out;

  signed char* xq = (signed char*)d_ws;
  float*       xs = (float*)((char*)d_ws + XQ_BYTES);

  if (ws_size >= WS_NEED) {
    // fast path: fused prep (rowquant + PW transpose) + 4-phase gemm
    unsigned* pwt = (unsigned*)((char*)d_ws + PWT_OFF);
    prep<<<dim3(TOKENS / 4 + 256), dim3(256), 0, stream>>>(x, xq, xs, pw, pwt);
    dim3 grid(OUT_F / BN, TOKENS / BM);  // (16, 32)
    gemm_i8<<<grid, dim3(NTHR), 0, stream>>>(xq, pwt, xs, sc, out);
  } else {
    // fallback: verified baseline gemm, inline ternary unpack (fits 33.6 MB ws)
    prep<<<dim3(TOKENS / 4), dim3(256), 0, stream>>>(x, xq, xs, pw, nullptr);
    dim3 grid(OUT_F / 128, TOKENS / 256);  // (32, 32)
    gemm_i8_pw<<<grid, dim3(256), 0, stream>>>(xq, pw, xs, sc, out);
  }
}